// Round 6
// baseline (306.802 us; speedup 1.0000x reference)
//
#include <hip/hip_runtime.h>
#include <hip/hip_bf16.h>

// SMPL-X LBS forward. B=512, V=10475, J=55. f32 in/out; fp16 MFMA internally.
//
//  k_prep  : fused independent prep (one launch):
//            blocks [0,7872)    PDH = pd^T f16 packed A-frags, NO-LDS transpose:
//                               thread owns (n, 8 consecutive k) -> 8 coalesced
//                               row-segment loads, one contiguous f16x8 store.
//            blocks [7872,+123) s_dirs = v_template + shape.shapedirs
//            block  +1          y_offset
//            blocks [+164)      lwT packed MFMA-fragment-major [vtile][ks][lane][8]
//            blocks [+165)      Js = Jreg@s_dirs (inline), JE = Jreg@exprdirs
//  k_batch : Rodrigues -> PFH packed; chain (shfl) -> AH packed [b][ks][lane][8]
//  k_pose  : D[n][b] = PDH x PFH, all frag loads coalesced from global (no LDS,
//            no barriers); +s_dirs -> VPH2. grid (492, 2 b-halves).
//  k_lbs   : T = AH x lwT (packed coalesced frag loads); VPH2 slice in LDS;
//            epilogue staged in LDS -> monotonic contiguous f32 stores

typedef _Float16 f16;
typedef f16  f16x8 __attribute__((ext_vector_type(8)));
typedef f16  f16x4 __attribute__((ext_vector_type(4)));
typedef float f32x4 __attribute__((ext_vector_type(4)));

#define VN    10475
#define JN    55
#define BN    512
#define VC3   31425
#define NPAD  31488          // 492*64
#define VPADV 10496

// f32 ws region (float offsets):
#define SD_F  0              // s_dirs [VC3]
#define JS_F  31425          // [165]
#define JE_F  31590          // [1650]
#define Y_F   33240
// byte offsets:
#define PFH_BYTE  (160*1024)           // f16 packed [32][16][64][8]  = 512 KB
#define AH_BYTE   (768*1024)           // f16 packed [512][2][64][8]  = 1 MB
#define VPH_BYTE  (2*1024*1024)        // f16 [512][31488] = 30.75 MB
#define LWT_BYTE  (34*1024*1024)       // f16 packed [656][2][64][8]  = 1.3 MB
// PDH (32.25 MB) is placed in d_out (64.3 MB), fully dead before k_lbs writes.

// prep block ranges: PDT first (longest pole dispatches earliest)
#define NB_PDT  (492*16)     // 7872: (n-block 0..491) x (k-group 0..15)
#define NB_SD   123
#define NB_LWT  164
#define NB_JREG 165
#define NB_PREP (NB_PDT + NB_SD + 1 + NB_LWT + NB_JREG)   // 8325

// ---------------- kernel 1: fused prep ----------------
__global__ __launch_bounds__(256) void k_prep(
    const float* __restrict__ vt, const float* __restrict__ shapedirs,
    const float* __restrict__ shape, const float* __restrict__ lw,
    const float* __restrict__ jr, const float* __restrict__ exprdirs,
    const float* __restrict__ pd, const float* __restrict__ ed,
    float* __restrict__ ws, f16* __restrict__ lwT, f16* __restrict__ PDH)
{
    __shared__ float red[256];        // 1 KB, used by reduction branches only
    const int bb  = blockIdx.x;
    const int tid = threadIdx.x;

    if (bb < NB_PDT) {
        // ---- PDH no-LDS transpose ----
        // block (bx, ky): cols n0..n0+63, k-range ky*32..+31.
        // thread: n = n0 + (tid&63), k0 = ky*32 + (tid>>6)*8.
        // 8 loads: lane-coalesced 256B row segments; 1 store: contiguous 16B.
        const int ky = bb / 492;
        const int bx = bb - ky * 492;
        const int n  = bx * 64 + (tid & 63);
        const int w  = tid >> 6;              // 0..3
        const int k0 = ky * 32 + w * 8;
        f16 h[8];
        #pragma unroll
        for (int e = 0; e < 8; ++e) {
            int k = k0 + e;
            float x = 0.f;
            if (n < VC3) {
                if (k < 486)      x = pd[(size_t)k * VC3 + n];
                else if (k < 496) x = ed[(size_t)n * 10 + (k - 486)];
            }
            h[e] = (f16)x;
        }
        // packed addr: tile = n>>4, kc = ky, lane' = w*16 + (n&15)
        *(f16x8*)&PDH[(size_t)(n >> 4) * 8192 + ky * 512 + (w * 16 + (tid & 15)) * 8]
            = *(f16x8*)&h[0];
    } else if (bb < NB_PDT + NB_SD) {
        // ---- s_dirs ----
        int i = (bb - NB_PDT) * 256 + tid;
        if (i < VC3) {
            float acc = vt[i];
            const float* sd = shapedirs + (size_t)i * 10;
            #pragma unroll
            for (int s = 0; s < 10; ++s) acc += shape[s] * sd[s];
            ws[SD_F + i] = acc;
        }
    } else if (bb == NB_PDT + NB_SD) {
        // ---- y_offset ----
        float m = 3.0e38f;
        for (int v = tid; v < VN; v += 256) m = fminf(m, vt[v*3 + 1]);
        red[tid] = m;
        __syncthreads();
        for (int s = 128; s > 0; s >>= 1) {
            if (tid < s) red[tid] = fminf(red[tid], red[tid + s]);
            __syncthreads();
        }
        if (tid == 0) ws[Y_F] = -red[0];
    } else if (bb < NB_PDT + NB_SD + 1 + NB_LWT) {
        // ---- lwT packed: lwT[vt*1024 + ks*512 + (q*16 + lv)*8 + e] ----
        int bx = bb - (NB_PDT + NB_SD + 1);
        int v  = bx * 64 + (tid >> 2);
        int jg = (tid & 3) * 16;
        f16 tmp[16];
        #pragma unroll
        for (int jj = 0; jj < 16; ++jj) {
            int j = jg + jj;
            tmp[jj] = (f16)((v < VN && j < JN) ? lw[(size_t)v*JN + j] : 0.f);
        }
        int vtile = v >> 4, lv = v & 15;
        int ks = jg >> 5, q0 = (jg >> 3) & 3;
        *(f16x8*)&lwT[(size_t)vtile*1024 + ks*512 + (q0*16 + lv)*8]     = *(f16x8*)&tmp[0];
        *(f16x8*)&lwT[(size_t)vtile*1024 + ks*512 + ((q0+1)*16 + lv)*8] = *(f16x8*)&tmp[8];
    } else {
        // ---- jreg (s_dirs recomputed inline -> no dep on s_dirs blocks) ----
        int jb = bb - (NB_PDT + NB_SD + 1 + NB_LWT);
        int j = jb / 3, c = jb % 3;
        float acc[11];
        #pragma unroll
        for (int i = 0; i < 11; ++i) acc[i] = 0.f;
        for (int v = tid; v < VN; v += 256) {
            float w = jr[(size_t)j * VN + v];
            float sv = vt[v*3 + c];
            const float* sd = shapedirs + (size_t)(v*3 + c) * 10;
            #pragma unroll
            for (int s = 0; s < 10; ++s) sv += shape[s] * sd[s];
            acc[10] += w * sv;
            const float* edp = exprdirs + (size_t)(v*3 + c) * 10;
            #pragma unroll
            for (int e = 0; e < 10; ++e) acc[e] += w * edp[e];
        }
        for (int i = 0; i < 11; ++i) {
            red[tid] = acc[i];
            __syncthreads();
            for (int s = 128; s > 0; s >>= 1) {
                if (tid < s) red[tid] += red[tid + s];
                __syncthreads();
            }
            if (tid == 0) {
                if (i == 10) ws[JS_F + j*3 + c] = red[0];
                else         ws[JE_F + (j*3 + c)*10 + i] = red[0];
            }
            __syncthreads();
        }
    }
}

// ---------------- kernel 2: per-batch pose prep ----------------
// PFH packed: PFH[((b>>4)*16 + (k>>5))*512 + (((k>>3)&3)*16 + (b&15))*8 + (k&7)]
// AH  packed: AH[b*1024 + (j>>5)*512 + (((j>>3)&3)*16 + row)*8 + (j&7)]
__global__ void k_batch(const float* __restrict__ body, const float* __restrict__ hand,
                        const float* __restrict__ head, const float* __restrict__ expr,
                        const float* __restrict__ pelvis, const float* __restrict__ hand_mean,
                        const float* __restrict__ ws, f16* __restrict__ PFH,
                        f16* __restrict__ AH)
{
    int b = blockIdx.x, tid = threadIdx.x;
    __shared__ float rot[JN][9];
    __shared__ float jnt[JN][3];

    f16* AHb = AH + (size_t)b * 1024;
    #pragma unroll
    for (int i = 0; i < 16; ++i) AHb[tid + i*64] = (f16)0.f;

    if (tid < JN) {
        int j = tid;
        float r0, r1, r2;
        if (j == 0) {
            r0 = pelvis[b*3+0]; r1 = pelvis[b*3+1]; r2 = pelvis[b*3+2];
        } else if (j <= 21) {
            int o = b*63 + (j-1)*3;
            r0 = body[o]; r1 = body[o+1]; r2 = body[o+2];
        } else if (j <= 24) {
            int o = b*9 + (j-22)*3;
            r0 = head[o]; r1 = head[o+1]; r2 = head[o+2];
        } else {
            int h = (j-25)*3;
            r0 = hand[b*90+h+0] + hand_mean[h+0];
            r1 = hand[b*90+h+1] + hand_mean[h+1];
            r2 = hand[b*90+h+2] + hand_mean[h+2];
        }
        float a2  = r0*r0 + r1*r1 + r2*r2 + 1e-12f;
        float ang = sqrtf(a2);
        float inv = 1.0f / ang;
        float kx = r0*inv, ky = r1*inv, kz = r2*inv;
        float s = sinf(ang), c = cosf(ang), ic = 1.0f - c;
        rot[j][0] = c + ic*kx*kx;    rot[j][1] = ic*kx*ky - s*kz; rot[j][2] = ic*kx*kz + s*ky;
        rot[j][3] = ic*kx*ky + s*kz; rot[j][4] = c + ic*ky*ky;    rot[j][5] = ic*ky*kz - s*kx;
        rot[j][6] = ic*kx*kz - s*ky; rot[j][7] = ic*ky*kz + s*kx; rot[j][8] = c + ic*kz*kz;
        #pragma unroll
        for (int cc = 0; cc < 3; ++cc) {
            float acc = ws[JS_F + j*3 + cc];
            #pragma unroll
            for (int e = 0; e < 10; ++e)
                acc += expr[b*10 + e] * ws[JE_F + (j*3 + cc)*10 + e];
            jnt[j][cc] = acc;
        }
    }
    __syncthreads();

    // PFH row b (packed): [0..486) pose_feature | [486..496) expr | rest zero
    #pragma unroll
    for (int i = 0; i < 8; ++i) {
        int k = tid + i*64;
        float val = 0.f;
        if (k < 486) {
            int jj = k/9 + 1, ii = k%9;
            float d = (ii == 0 || ii == 4 || ii == 8) ? 1.0f : 0.0f;
            val = rot[jj][ii] - d;
        } else if (k < 496) {
            val = expr[b*10 + (k-486)];
        }
        PFH[(size_t)((b>>4)*16 + (k>>5))*512 + (((k>>3)&3)*16 + (b&15))*8 + (k&7)] = (f16)val;
    }

    // G chain: single wave, registers + shuffles, no barriers.
    int r = tid >> 2, cc = tid & 3;
    float g = 0.f;
    if (tid < 12) g = (cc < 3) ? rot[0][r*3 + cc] : jnt[0][r];
    for (int j = 0; j < JN; ++j) {
        if (j > 0) {
            float g0 = __shfl(g, r*4+0), g1 = __shfl(g, r*4+1);
            float g2 = __shfl(g, r*4+2), g3 = __shfl(g, r*4+3);
            if (cc < 3) g = g0*rot[j][cc] + g1*rot[j][3+cc] + g2*rot[j][6+cc];
            else        g = g0*(jnt[j][0]-jnt[j-1][0]) + g1*(jnt[j][1]-jnt[j-1][1])
                          + g2*(jnt[j][2]-jnt[j-1][2]) + g3;
        }
        float h0 = __shfl(g, r*4+0), h1 = __shfl(g, r*4+1), h2 = __shfl(g, r*4+2);
        float aval = g;
        if (cc == 3) aval = g - (h0*jnt[j][0] + h1*jnt[j][1] + h2*jnt[j][2]);
        if (tid < 12)
            AHb[(j>>5)*512 + (((j>>3)&3)*16 + tid)*8 + (j&7)] = (f16)aval;
    }
}

// ---------------- kernel 3: pose GEMM, all-global streaming ----------------
// Block: 64 n-cols x 256 batches, K=512. grid (492, 2). af from PDH packed,
// bf from PFH packed — every load a coalesced 1KB fragment. No LDS/barriers.
// acc[4][4] = 64 VGPR. Epilogue: direct f16x4 stores (32B/4-lane chunks).
__global__ __launch_bounds__(256) void k_pose(
    const float* __restrict__ ws, const f16* __restrict__ PDH,
    const f16* __restrict__ PFH, f16* __restrict__ VPH2)
{
    const int t = threadIdx.x;
    const int bx = blockIdx.x;           // n-tile group: cols bx*64..+63
    const int by = blockIdx.y;           // b-half: batches by*256..+255
    const int n0 = bx * 64;
    const int w = t >> 6, lane = t & 63, l = lane & 15, q = lane >> 4;

    f32x4 acc[4][4];
    #pragma unroll
    for (int i = 0; i < 4; ++i)
        #pragma unroll
        for (int j = 0; j < 4; ++j) acc[i][j] = (f32x4)0.f;

    for (int kc = 0; kc < 16; ++kc) {
        f16x8 af[4], bf[4];
        #pragma unroll
        for (int mt = 0; mt < 4; ++mt)
            af[mt] = *(const f16x8*)&PDH[(size_t)(4*bx + mt)*8192 + kc*512 + lane*8];
        #pragma unroll
        for (int nt = 0; nt < 4; ++nt)
            bf[nt] = *(const f16x8*)&PFH[(size_t)((by*16 + w*4 + nt)*16 + kc)*512 + lane*8];
        #pragma unroll
        for (int mt = 0; mt < 4; ++mt)
            #pragma unroll
            for (int nt = 0; nt < 4; ++nt)
                acc[mt][nt] = __builtin_amdgcn_mfma_f32_16x16x32_f16(af[mt], bf[nt], acc[mt][nt], 0, 0, 0);
    }

    // lane (l,q) reg i: D[n = n0 + mt*16 + q*4 + i][b = by*256 + w*64 + nt*16 + l]
    #pragma unroll
    for (int mt = 0; mt < 4; ++mt) {
        int nb2 = n0 + mt*16 + q*4;
        float sdv[4];
        #pragma unroll
        for (int i = 0; i < 4; ++i)
            sdv[i] = (nb2 + i < VC3) ? ws[SD_F + nb2 + i] : 0.f;
        #pragma unroll
        for (int nt = 0; nt < 4; ++nt) {
            int b = by*256 + w*64 + nt*16 + l;
            f16 pack[4];
            #pragma unroll
            for (int i = 0; i < 4; ++i)
                pack[i] = (f16)(acc[mt][nt][i] + sdv[i]);
            *(f16x4*)&VPH2[(size_t)b*NPAD + nb2] = *(f16x4*)&pack[0];
        }
    }
}

// ---------------- kernel 4: LBS GEMM + epilogue ----------------
// Block: 64 verts x 128 m2-rows (wave owns 32 m2 = 2 batches). A/B frag loads
// fully coalesced from packed AH / lwT. VPH2 slice staged in LDS. Output
// staged in LDS then written with monotonic contiguous dword stores.
__global__ __launch_bounds__(256, 8) void k_lbs(
    const float* __restrict__ gt, const float* __restrict__ ws,
    const f16* __restrict__ AH, const f16* __restrict__ lwT,
    const f16* __restrict__ VPH2, float* __restrict__ out)
{
    __shared__ f16   LV[8*192];      // 3 KB
    __shared__ float OUTS[8*192];    // 6 KB
    const int t = threadIdx.x;
    const int v0 = blockIdx.x * 64;
    const int bbase = blockIdx.y * 8;
    const int w = t >> 6, lane = t & 63, l = lane & 15, q = lane >> 4;

    if (t < 192) {                  // stage VPH2 slice: 8 b x 384 B
        int bl = t / 24, c8 = t % 24;
        *(f16x8*)&LV[bl*192 + c8*8] =
            *(const f16x8*)&VPH2[(size_t)(bbase + bl)*NPAD + v0*3 + c8*8];
    }
    __syncthreads();

    f32x4 acc[2][4];
    #pragma unroll
    for (int i = 0; i < 2; ++i)
        #pragma unroll
        for (int j = 0; j < 4; ++j) acc[i][j] = (f32x4)0.f;

    #pragma unroll
    for (int ks = 0; ks < 2; ++ks) {
        f16x8 af[2], bf[4];
        #pragma unroll
        for (int nt = 0; nt < 4; ++nt)
            bf[nt] = *(const f16x8*)&lwT[(size_t)(blockIdx.x*4 + nt)*1024 + ks*512 + lane*8];
        #pragma unroll
        for (int mt = 0; mt < 2; ++mt)
            af[mt] = *(const f16x8*)&AH[(size_t)(bbase + w*2 + mt)*1024 + ks*512 + lane*8];
        #pragma unroll
        for (int mt = 0; mt < 2; ++mt)
            #pragma unroll
            for (int nt = 0; nt < 4; ++nt)
                acc[mt][nt] = __builtin_amdgcn_mfma_f32_16x16x32_f16(af[mt], bf[nt], acc[mt][nt], 0, 0, 0);
    }

    // lane (l,q) reg i: D[m2][v = v0 + nt*16 + l] => b = bbase + w*2 + mt, r=q, c=i
    float yoff = ws[Y_F];
    #pragma unroll
    for (int mt = 0; mt < 2; ++mt) {
        int bl = w*2 + mt;
        float add = 0.f;
        if (q < 3) add = gt[(bbase + bl)*3 + q] + (q == 1 ? yoff : 0.f);
        const f16* vrow = &LV[bl*192];
        #pragma unroll
        for (int nt = 0; nt < 4; ++nt) {
            if (q < 3) {
                int o = (nt*16 + l)*3;
                float vx = (float)vrow[o], vy = (float)vrow[o+1], vz = (float)vrow[o+2];
                f32x4 T = acc[mt][nt];
                OUTS[bl*192 + o + q] = T[0]*vx + T[1]*vy + T[2]*vz + T[3] + add;
            }
        }
    }
    __syncthreads();
    // monotonic contiguous stores: thread t writes ascending dwords
    #pragma unroll
    for (int pass = 0; pass < 6; ++pass) {
        int idx = pass*256 + t;            // 0..1535
        int bl  = idx / 192;
        int c   = idx - bl*192;
        if (v0*3 + c < VC3)                // VN*3 == VC3
            out[(size_t)(bbase + bl)*VC3 + v0*3 + c] = OUTS[idx];
    }
}

extern "C" void kernel_launch(void* const* d_in, const int* in_sizes, int n_in,
                              void* d_out, int out_size, void* d_ws, size_t ws_size,
                              hipStream_t stream)
{
    const float* shape  = (const float*)d_in[0];
    const float* body   = (const float*)d_in[1];
    const float* hand   = (const float*)d_in[2];
    const float* head   = (const float*)d_in[3];
    const float* expr   = (const float*)d_in[4];
    const float* pelvis = (const float*)d_in[5];
    const float* gtrans = (const float*)d_in[6];
    const float* vt     = (const float*)d_in[7];
    const float* shdirs = (const float*)d_in[8];
    const float* exdirs = (const float*)d_in[9];
    const float* pdirs  = (const float*)d_in[10];
    const float* lbsw   = (const float*)d_in[11];
    const float* jreg   = (const float*)d_in[12];
    const float* hmean  = (const float*)d_in[13];
    float* wsf  = (float*)d_ws;
    f16*   PFH  = (f16*)((char*)d_ws + PFH_BYTE);
    f16*   AH   = (f16*)((char*)d_ws + AH_BYTE);
    f16*   VPH2 = (f16*)((char*)d_ws + VPH_BYTE);
    f16*   lwT  = (f16*)((char*)d_ws + LWT_BYTE);
    f16*   PDH  = (f16*)d_out;        // 32.25 MB scratch, dead before k_lbs
    float* out  = (float*)d_out;

    hipLaunchKernelGGL(k_prep,  dim3(NB_PREP), dim3(256), 0, stream,
                       vt, shdirs, shape, lbsw, jreg, exdirs, pdirs, exdirs, wsf, lwT, PDH);
    hipLaunchKernelGGL(k_batch, dim3(BN),   dim3(64),  0, stream,
                       body, hand, head, expr, pelvis, hmean, wsf, PFH, AH);
    hipLaunchKernelGGL(k_pose,  dim3(NPAD/64, 2), dim3(256), 0, stream,
                       wsf, PDH, PFH, VPH2);
    hipLaunchKernelGGL(k_lbs,   dim3(VPADV/64, 8192/128), dim3(256), 0, stream,
                       gtrans, wsf, AH, lwT, VPH2, out);
}

// Round 7
// 247.963 us; speedup vs baseline: 1.2373x; 1.2373x over previous
//
#include <hip/hip_runtime.h>
#include <hip/hip_bf16.h>

// SMPL-X LBS forward. B=512, V=10475, J=55. f32 in/out; fp16 MFMA internally.
//
//  k_prep  : fused independent prep (one launch):
//            blocks [0,123)    s_dirs = v_template + shape.shapedirs
//            block  123        y_offset
//            blocks [124,288)  lwT packed MFMA-fragment-major [vtile][ks][lane][8]
//            blocks [288,453)  Js = Jreg@s_dirs (inline), JE = Jreg@exprdirs
//  k_batch : Rodrigues -> PFH packed; chain (shfl) -> AH packed [b][ks][lane][8]
//  k_pose  : inline pd transpose (split-K LDS staging, 37 KB) x PFH packed.
//            8 waves/block, wave tile 32c x 64b, acc[2][4]=32 AGPR -> total
//            regs <=128 -> 4 waves/SIMD (2x round-2 occupancy). grid (492,2).
//  k_lbs   : T = AH x lwT (packed coalesced frag loads); VPH2 slice in LDS;
//            epilogue staged in LDS -> monotonic contiguous f32 stores

typedef _Float16 f16;
typedef f16  f16x8 __attribute__((ext_vector_type(8)));
typedef f16  f16x4 __attribute__((ext_vector_type(4)));
typedef float f32x4 __attribute__((ext_vector_type(4)));

#define VN    10475
#define JN    55
#define BN    512
#define VC3   31425
#define NPAD  31488          // 492*64
#define VPADV 10496

// f32 ws region (float offsets):
#define SD_F  0              // s_dirs [VC3]
#define JS_F  31425          // [165]
#define JE_F  31590          // [1650]
#define Y_F   33240
// byte offsets:
#define PFH_BYTE  (160*1024)           // f16 packed [32][16][64][8]  = 512 KB
#define AH_BYTE   (768*1024)           // f16 packed [512][2][64][8]  = 1 MB
#define VPH_BYTE  (2*1024*1024)        // f16 [512][31488] = 30.75 MB
#define LWT_BYTE  (34*1024*1024)       // f16 packed [656][2][64][8]  = 1.3 MB

// prep block ranges
#define NB_SD   123
#define NB_LWT  164
#define NB_JREG 165
#define NB_PREP (NB_SD + 1 + NB_LWT + NB_JREG)   // 453

// ---------------- kernel 1: fused prep ----------------
__global__ __launch_bounds__(256) void k_prep(
    const float* __restrict__ vt, const float* __restrict__ shapedirs,
    const float* __restrict__ shape, const float* __restrict__ lw,
    const float* __restrict__ jr, const float* __restrict__ exprdirs,
    float* __restrict__ ws, f16* __restrict__ lwT)
{
    __shared__ float red[256];
    const int bb  = blockIdx.x;
    const int tid = threadIdx.x;

    if (bb < NB_SD) {
        // ---- s_dirs ----
        int i = bb * 256 + tid;
        if (i < VC3) {
            float acc = vt[i];
            const float* sd = shapedirs + (size_t)i * 10;
            #pragma unroll
            for (int s = 0; s < 10; ++s) acc += shape[s] * sd[s];
            ws[SD_F + i] = acc;
        }
    } else if (bb == NB_SD) {
        // ---- y_offset ----
        float m = 3.0e38f;
        for (int v = tid; v < VN; v += 256) m = fminf(m, vt[v*3 + 1]);
        red[tid] = m;
        __syncthreads();
        for (int s = 128; s > 0; s >>= 1) {
            if (tid < s) red[tid] = fminf(red[tid], red[tid + s]);
            __syncthreads();
        }
        if (tid == 0) ws[Y_F] = -red[0];
    } else if (bb < NB_SD + 1 + NB_LWT) {
        // ---- lwT packed: lwT[vt*1024 + ks*512 + (q*16 + lv)*8 + e] ----
        int bx = bb - (NB_SD + 1);
        int v  = bx * 64 + (tid >> 2);
        int jg = (tid & 3) * 16;
        f16 tmp[16];
        #pragma unroll
        for (int jj = 0; jj < 16; ++jj) {
            int j = jg + jj;
            tmp[jj] = (f16)((v < VN && j < JN) ? lw[(size_t)v*JN + j] : 0.f);
        }
        int vtile = v >> 4, lv = v & 15;
        int ks = jg >> 5, q0 = (jg >> 3) & 3;
        *(f16x8*)&lwT[(size_t)vtile*1024 + ks*512 + (q0*16 + lv)*8]     = *(f16x8*)&tmp[0];
        *(f16x8*)&lwT[(size_t)vtile*1024 + ks*512 + ((q0+1)*16 + lv)*8] = *(f16x8*)&tmp[8];
    } else {
        // ---- jreg (s_dirs recomputed inline -> no dep on s_dirs blocks) ----
        int jb = bb - (NB_SD + 1 + NB_LWT);
        int j = jb / 3, c = jb % 3;
        float acc[11];
        #pragma unroll
        for (int i = 0; i < 11; ++i) acc[i] = 0.f;
        for (int v = tid; v < VN; v += 256) {
            float w = jr[(size_t)j * VN + v];
            float sv = vt[v*3 + c];
            const float* sd = shapedirs + (size_t)(v*3 + c) * 10;
            #pragma unroll
            for (int s = 0; s < 10; ++s) sv += shape[s] * sd[s];
            acc[10] += w * sv;
            const float* edp = exprdirs + (size_t)(v*3 + c) * 10;
            #pragma unroll
            for (int e = 0; e < 10; ++e) acc[e] += w * edp[e];
        }
        for (int i = 0; i < 11; ++i) {
            red[tid] = acc[i];
            __syncthreads();
            for (int s = 128; s > 0; s >>= 1) {
                if (tid < s) red[tid] += red[tid + s];
                __syncthreads();
            }
            if (tid == 0) {
                if (i == 10) ws[JS_F + j*3 + c] = red[0];
                else         ws[JE_F + (j*3 + c)*10 + i] = red[0];
            }
            __syncthreads();
        }
    }
}

// ---------------- kernel 2: per-batch pose prep ----------------
// PFH packed: PFH[((b>>4)*16 + (k>>5))*512 + (((k>>3)&3)*16 + (b&15))*8 + (k&7)]
// AH  packed: AH[b*1024 + (j>>5)*512 + (((j>>3)&3)*16 + row)*8 + (j&7)]
__global__ void k_batch(const float* __restrict__ body, const float* __restrict__ hand,
                        const float* __restrict__ head, const float* __restrict__ expr,
                        const float* __restrict__ pelvis, const float* __restrict__ hand_mean,
                        const float* __restrict__ ws, f16* __restrict__ PFH,
                        f16* __restrict__ AH)
{
    int b = blockIdx.x, tid = threadIdx.x;
    __shared__ float rot[JN][9];
    __shared__ float jnt[JN][3];

    f16* AHb = AH + (size_t)b * 1024;
    #pragma unroll
    for (int i = 0; i < 16; ++i) AHb[tid + i*64] = (f16)0.f;

    if (tid < JN) {
        int j = tid;
        float r0, r1, r2;
        if (j == 0) {
            r0 = pelvis[b*3+0]; r1 = pelvis[b*3+1]; r2 = pelvis[b*3+2];
        } else if (j <= 21) {
            int o = b*63 + (j-1)*3;
            r0 = body[o]; r1 = body[o+1]; r2 = body[o+2];
        } else if (j <= 24) {
            int o = b*9 + (j-22)*3;
            r0 = head[o]; r1 = head[o+1]; r2 = head[o+2];
        } else {
            int h = (j-25)*3;
            r0 = hand[b*90+h+0] + hand_mean[h+0];
            r1 = hand[b*90+h+1] + hand_mean[h+1];
            r2 = hand[b*90+h+2] + hand_mean[h+2];
        }
        float a2  = r0*r0 + r1*r1 + r2*r2 + 1e-12f;
        float ang = sqrtf(a2);
        float inv = 1.0f / ang;
        float kx = r0*inv, ky = r1*inv, kz = r2*inv;
        float s = sinf(ang), c = cosf(ang), ic = 1.0f - c;
        rot[j][0] = c + ic*kx*kx;    rot[j][1] = ic*kx*ky - s*kz; rot[j][2] = ic*kx*kz + s*ky;
        rot[j][3] = ic*kx*ky + s*kz; rot[j][4] = c + ic*ky*ky;    rot[j][5] = ic*ky*kz - s*kx;
        rot[j][6] = ic*kx*kz - s*ky; rot[j][7] = ic*ky*kz + s*kx; rot[j][8] = c + ic*kz*kz;
        #pragma unroll
        for (int cc = 0; cc < 3; ++cc) {
            float acc = ws[JS_F + j*3 + cc];
            #pragma unroll
            for (int e = 0; e < 10; ++e)
                acc += expr[b*10 + e] * ws[JE_F + (j*3 + cc)*10 + e];
            jnt[j][cc] = acc;
        }
    }
    __syncthreads();

    // PFH row b (packed): [0..486) pose_feature | [486..496) expr | rest zero
    #pragma unroll
    for (int i = 0; i < 8; ++i) {
        int k = tid + i*64;
        float val = 0.f;
        if (k < 486) {
            int jj = k/9 + 1, ii = k%9;
            float d = (ii == 0 || ii == 4 || ii == 8) ? 1.0f : 0.0f;
            val = rot[jj][ii] - d;
        } else if (k < 496) {
            val = expr[b*10 + (k-486)];
        }
        PFH[(size_t)((b>>4)*16 + (k>>5))*512 + (((k>>3)&3)*16 + (b&15))*8 + (k&7)] = (f16)val;
    }

    // G chain: single wave, registers + shuffles, no barriers.
    int r = tid >> 2, cc = tid & 3;
    float g = 0.f;
    if (tid < 12) g = (cc < 3) ? rot[0][r*3 + cc] : jnt[0][r];
    for (int j = 0; j < JN; ++j) {
        if (j > 0) {
            float g0 = __shfl(g, r*4+0), g1 = __shfl(g, r*4+1);
            float g2 = __shfl(g, r*4+2), g3 = __shfl(g, r*4+3);
            if (cc < 3) g = g0*rot[j][cc] + g1*rot[j][3+cc] + g2*rot[j][6+cc];
            else        g = g0*(jnt[j][0]-jnt[j-1][0]) + g1*(jnt[j][1]-jnt[j-1][1])
                          + g2*(jnt[j][2]-jnt[j-1][2]) + g3;
        }
        float h0 = __shfl(g, r*4+0), h1 = __shfl(g, r*4+1), h2 = __shfl(g, r*4+2);
        float aval = g;
        if (cc == 3) aval = g - (h0*jnt[j][0] + h1*jnt[j][1] + h2*jnt[j][2]);
        if (tid < 12)
            AHb[(j>>5)*512 + (((j>>3)&3)*16 + tid)*8 + (j&7)] = (f16)aval;
    }
}

// ---------------- kernel 3: pose GEMM, register-light ----------------
// 512 thr = 8 waves (2 col-groups x 4 batch-groups); block = 64 cols x 256 b;
// grid (492, 2). Split-K: pd tile staged as f16 [c][256k] twice (33 KB).
// acc[2][4] = 32 AGPR/wave; target total regs <=128 -> 4 waves/SIMD.
#define BTS2 264                    // stage row stride (halves), 16B-aligned
#define LTS 72                      // epilogue L[b][c] stride (halves)
__global__ __launch_bounds__(512, 4) void k_pose(
    const float* __restrict__ pd, const float* __restrict__ ed,
    const float* __restrict__ ws, const f16* __restrict__ PFH,
    f16* __restrict__ VPH2)
{
    __shared__ f16 SH[256*LTS];     // 18432 halves = 36864 B; stage uses 64*264
    __shared__ float SDl[64];
    const int t = threadIdx.x;
    const int n0 = blockIdx.x * 64;
    const int by = blockIdx.y;      // batch half
    const int w = t >> 6, lane = t & 63, l = lane & 15, q = lane >> 4;
    const int wm = w >> 2, wb = w & 3;
    f16* Bt = SH;

    if (t < 64) { int n = n0 + t; SDl[t] = (n < VC3) ? ws[SD_F + n] : 0.f; }

    f32x4 acc[2][4];
    #pragma unroll
    for (int i = 0; i < 2; ++i)
        #pragma unroll
        for (int j = 0; j < 4; ++j) acc[i][j] = (f32x4)0.f;

    const int krow = t & 31, f = t >> 5;     // f 0..15 -> cols f*4..+3
    const int nb = n0 + f*4;

    for (int h = 0; h < 2; ++h) {
        // ---- stage K-half h: f32 [k][n] -> f16 LDS [c][klocal] ----
        #pragma unroll
        for (int it = 0; it < 8; ++it) {
            int k = h*256 + krow + it*32;
            float4 vv = make_float4(0.f, 0.f, 0.f, 0.f);
            if (k < 486) {
                if (nb + 3 < VC3) vv = *(const float4*)(pd + (size_t)k*VC3 + nb);
                else {
                    float* pv = (float*)&vv;
                    for (int e = 0; e < 4; ++e)
                        if (nb + e < VC3) pv[e] = pd[(size_t)k*VC3 + nb + e];
                }
            } else if (k < 496) {
                float* pv = (float*)&vv;
                for (int e = 0; e < 4; ++e)
                    if (nb + e < VC3) pv[e] = ed[(size_t)(nb + e)*10 + (k - 486)];
            }
            int kl = krow + it*32;
            Bt[(f*4+0)*BTS2 + kl] = (f16)vv.x;
            Bt[(f*4+1)*BTS2 + kl] = (f16)vv.y;
            Bt[(f*4+2)*BTS2 + kl] = (f16)vv.z;
            Bt[(f*4+3)*BTS2 + kl] = (f16)vv.w;
        }
        __syncthreads();
        // ---- compute on half h ----
        #pragma unroll
        for (int kc8 = 0; kc8 < 8; ++kc8) {
            int kc = h*8 + kc8;
            f16x8 af[2], bf[4];
            #pragma unroll
            for (int mt = 0; mt < 2; ++mt)
                af[mt] = *(const f16x8*)&Bt[(wm*32 + mt*16 + l)*BTS2 + kc8*32 + q*8];
            #pragma unroll
            for (int nt = 0; nt < 4; ++nt)
                bf[nt] = *(const f16x8*)&PFH[(size_t)((by*16 + wb*4 + nt)*16 + kc)*512 + lane*8];
            #pragma unroll
            for (int mt = 0; mt < 2; ++mt)
                #pragma unroll
                for (int nt = 0; nt < 4; ++nt)
                    acc[mt][nt] = __builtin_amdgcn_mfma_f32_16x16x32_f16(af[mt], bf[nt], acc[mt][nt], 0, 0, 0);
        }
        __syncthreads();            // all waves done with Bt before overwrite
    }

    // ---- epilogue: lane holds D[c = wm*32+mt*16+q*4+i][b = by*256+wb*64+nt*16+l]
    f16* L = SH;                    // [b_local][c] stride LTS (256 x 72)
    #pragma unroll
    for (int mt = 0; mt < 2; ++mt)
        #pragma unroll
        for (int nt = 0; nt < 4; ++nt) {
            int bl = wb*64 + nt*16 + l;
            f16 pack[4];
            #pragma unroll
            for (int i = 0; i < 4; ++i) {
                int c = wm*32 + mt*16 + q*4 + i;
                pack[i] = (f16)(acc[mt][nt][i] + SDl[c]);
            }
            *(f16x4*)&L[bl*LTS + wm*32 + mt*16 + q*4] = *(f16x4*)&pack[0];
        }
    __syncthreads();
    {   // coalesced f16x4 stores: 16 threads cover 64 cols, 32 b per pass
        const int c4 = (t & 15) * 4, bq = t >> 4;
        #pragma unroll
        for (int it = 0; it < 8; ++it) {
            int bl = bq + 32*it;
            *(f16x4*)&VPH2[(size_t)(by*256 + bl)*NPAD + n0 + c4] = *(const f16x4*)&L[bl*LTS + c4];
        }
    }
}

// ---------------- kernel 4: LBS GEMM + epilogue ----------------
// Block: 64 verts x 128 m2-rows (wave owns 32 m2 = 2 batches). A/B frag loads
// fully coalesced from packed AH / lwT. VPH2 slice staged in LDS. Output
// staged in LDS then written with monotonic contiguous dword stores.
__global__ __launch_bounds__(256, 8) void k_lbs(
    const float* __restrict__ gt, const float* __restrict__ ws,
    const f16* __restrict__ AH, const f16* __restrict__ lwT,
    const f16* __restrict__ VPH2, float* __restrict__ out)
{
    __shared__ f16   LV[8*192];      // 3 KB
    __shared__ float OUTS[8*192];    // 6 KB
    const int t = threadIdx.x;
    const int v0 = blockIdx.x * 64;
    const int bbase = blockIdx.y * 8;
    const int w = t >> 6, lane = t & 63, l = lane & 15, q = lane >> 4;

    if (t < 192) {                  // stage VPH2 slice: 8 b x 384 B
        int bl = t / 24, c8 = t % 24;
        *(f16x8*)&LV[bl*192 + c8*8] =
            *(const f16x8*)&VPH2[(size_t)(bbase + bl)*NPAD + v0*3 + c8*8];
    }
    __syncthreads();

    f32x4 acc[2][4];
    #pragma unroll
    for (int i = 0; i < 2; ++i)
        #pragma unroll
        for (int j = 0; j < 4; ++j) acc[i][j] = (f32x4)0.f;

    #pragma unroll
    for (int ks = 0; ks < 2; ++ks) {
        f16x8 af[2], bf[4];
        #pragma unroll
        for (int nt = 0; nt < 4; ++nt)
            bf[nt] = *(const f16x8*)&lwT[(size_t)(blockIdx.x*4 + nt)*1024 + ks*512 + lane*8];
        #pragma unroll
        for (int mt = 0; mt < 2; ++mt)
            af[mt] = *(const f16x8*)&AH[(size_t)(bbase + w*2 + mt)*1024 + ks*512 + lane*8];
        #pragma unroll
        for (int mt = 0; mt < 2; ++mt)
            #pragma unroll
            for (int nt = 0; nt < 4; ++nt)
                acc[mt][nt] = __builtin_amdgcn_mfma_f32_16x16x32_f16(af[mt], bf[nt], acc[mt][nt], 0, 0, 0);
    }

    // lane (l,q) reg i: D[m2][v = v0 + nt*16 + l] => b = bbase + w*2 + mt, r=q, c=i
    float yoff = ws[Y_F];
    #pragma unroll
    for (int mt = 0; mt < 2; ++mt) {
        int bl = w*2 + mt;
        float add = 0.f;
        if (q < 3) add = gt[(bbase + bl)*3 + q] + (q == 1 ? yoff : 0.f);
        const f16* vrow = &LV[bl*192];
        #pragma unroll
        for (int nt = 0; nt < 4; ++nt) {
            if (q < 3) {
                int o = (nt*16 + l)*3;
                float vx = (float)vrow[o], vy = (float)vrow[o+1], vz = (float)vrow[o+2];
                f32x4 T = acc[mt][nt];
                OUTS[bl*192 + o + q] = T[0]*vx + T[1]*vy + T[2]*vz + T[3] + add;
            }
        }
    }
    __syncthreads();
    // monotonic contiguous stores: thread t writes ascending dwords
    #pragma unroll
    for (int pass = 0; pass < 6; ++pass) {
        int idx = pass*256 + t;            // 0..1535
        int bl  = idx / 192;
        int c   = idx - bl*192;
        if (v0*3 + c < VC3)                // VN*3 == VC3
            out[(size_t)(bbase + bl)*VC3 + v0*3 + c] = OUTS[idx];
    }
}

extern "C" void kernel_launch(void* const* d_in, const int* in_sizes, int n_in,
                              void* d_out, int out_size, void* d_ws, size_t ws_size,
                              hipStream_t stream)
{
    const float* shape  = (const float*)d_in[0];
    const float* body   = (const float*)d_in[1];
    const float* hand   = (const float*)d_in[2];
    const float* head   = (const float*)d_in[3];
    const float* expr   = (const float*)d_in[4];
    const float* pelvis = (const float*)d_in[5];
    const float* gtrans = (const float*)d_in[6];
    const float* vt     = (const float*)d_in[7];
    const float* shdirs = (const float*)d_in[8];
    const float* exdirs = (const float*)d_in[9];
    const float* pdirs  = (const float*)d_in[10];
    const float* lbsw   = (const float*)d_in[11];
    const float* jreg   = (const float*)d_in[12];
    const float* hmean  = (const float*)d_in[13];
    float* wsf  = (float*)d_ws;
    f16*   PFH  = (f16*)((char*)d_ws + PFH_BYTE);
    f16*   AH   = (f16*)((char*)d_ws + AH_BYTE);
    f16*   VPH2 = (f16*)((char*)d_ws + VPH_BYTE);
    f16*   lwT  = (f16*)((char*)d_ws + LWT_BYTE);
    float* out  = (float*)d_out;

    hipLaunchKernelGGL(k_prep,  dim3(NB_PREP), dim3(256), 0, stream,
                       vt, shdirs, shape, lbsw, jreg, exdirs, wsf, lwT);
    hipLaunchKernelGGL(k_batch, dim3(BN),   dim3(64),  0, stream,
                       body, hand, head, expr, pelvis, hmean, wsf, PFH, AH);
    hipLaunchKernelGGL(k_pose,  dim3(NPAD/64, 2), dim3(512), 0, stream,
                       pdirs, exdirs, wsf, PFH, VPH2);
    hipLaunchKernelGGL(k_lbs,   dim3(VPADV/64, 8192/128), dim3(256), 0, stream,
                       gtrans, wsf, AH, lwT, VPH2, out);
}